// Round 3
// baseline (4645.788 us; speedup 1.0000x reference)
//
#include <hip/hip_runtime.h>
#include <hip/hip_bf16.h>

// Problem: BS=2, C=32, S=64.
// x (concat of 3 axial-attention branches): (2, 96, 64, 64, 64) fp32 in d_ws (192 MiB).
// out: (2, 32, 64, 64, 64) fp32.

#define SS 64
#define CH 32

// ---------------------------------------------------------------------------
// Axial attention, one block per (b, c, s). Unified form:
//   Qs[row][feat], Ks[row][feat]  (row = token index i/j, feat = contraction dim m)
//   A[i][j] = sum_t Qs[i][t] * Ks[j][t]   -> softmax over j
//   out[r][t] = sum_j A[r][j] * Vs[j][t]
// BR selects the global-memory addressing of the slice and the output channel.
// ---------------------------------------------------------------------------
template <int BR>
__global__ __launch_bounds__(256) void attn_kernel(const float* __restrict__ q,
                                                   const float* __restrict__ k,
                                                   const float* __restrict__ v,
                                                   float* __restrict__ x) {
  __shared__ float Qs[64][65];
  __shared__ float Ks[64][65];
  __shared__ float As[64][65];

  const int blk = blockIdx.x;
  const int s = blk & 63;
  const int c = (blk >> 6) & 31;
  const int b = blk >> 11;
  const int tid = threadIdx.x;
  const size_t base = ((size_t)(b * CH + c)) << 18;  // * 64^3

  // ---- stage Q, K ----
  for (int idx = tid; idx < 4096; idx += 256) {
    int r, t;
    size_t off;
    if (BR == 0) {
      // branch a: Q[m][i] at m*4096 + i*64 + s ; store transposed Qs[i][m].
      // lanes walk i (stride-64 global; best available since s is innermost+fixed)
      int m = idx >> 6, i = idx & 63;
      off = (size_t)m * 4096 + (size_t)i * 64 + (size_t)s;
      r = i; t = m;
    } else if (BR == 1) {
      // branch b: Q[i][m] at i*4096 + s*64 + m  (coalesced along m)
      int i = idx >> 6, m = idx & 63;
      off = (size_t)i * 4096 + (size_t)s * 64 + (size_t)m;
      r = i; t = m;
    } else {
      // branch c: Q[i][m] at s*4096 + i*64 + m  (fully contiguous)
      int i = idx >> 6, m = idx & 63;
      off = (size_t)s * 4096 + (size_t)i * 64 + (size_t)m;
      r = i; t = m;
    }
    Qs[r][t] = q[base + off];
    Ks[r][t] = k[base + off];
  }
  __syncthreads();

  // ---- scores: 4x4 register tile per thread ----
  {
    const int ti = (tid >> 4) * 4;   // i-tile
    const int tj = (tid & 15) * 4;   // j-tile
    float acc[4][4] = {};
    #pragma unroll 4
    for (int t = 0; t < 64; ++t) {
      float qv[4], kv[4];
      #pragma unroll
      for (int u = 0; u < 4; ++u) {
        qv[u] = Qs[ti + u][t];
        kv[u] = Ks[tj + u][t];
      }
      #pragma unroll
      for (int ui = 0; ui < 4; ++ui)
        #pragma unroll
        for (int uj = 0; uj < 4; ++uj)
          acc[ui][uj] += qv[ui] * kv[uj];
    }
    #pragma unroll
    for (int ui = 0; ui < 4; ++ui)
      #pragma unroll
      for (int uj = 0; uj < 4; ++uj)
        As[ti + ui][tj + uj] = acc[ui][uj];
  }
  __syncthreads();

  // ---- stage V into Qs (reuse) + softmax on As (independent, same sync pair) ----
  for (int idx = tid; idx < 4096; idx += 256) {
    int r, t;
    size_t off;
    if (BR == 0) {
      // V[j][w] at j*4096 + w*64 + s
      int j = idx >> 6, w = idx & 63;
      off = (size_t)j * 4096 + (size_t)w * 64 + (size_t)s;
      r = j; t = w;
    } else if (BR == 1) {
      int j = idx >> 6, m = idx & 63;
      off = (size_t)j * 4096 + (size_t)s * 64 + (size_t)m;
      r = j; t = m;
    } else {
      int j = idx >> 6, m = idx & 63;
      off = (size_t)s * 4096 + (size_t)j * 64 + (size_t)m;
      r = j; t = m;
    }
    Qs[r][t] = v[base + off];
  }
  if (tid < 64) {
    float mx = -1e30f;
    for (int j = 0; j < 64; ++j) mx = fmaxf(mx, As[tid][j]);
    float sum = 0.f;
    for (int j = 0; j < 64; ++j) {
      float e = __expf(As[tid][j] - mx);
      As[tid][j] = e;
      sum += e;
    }
    float inv = 1.f / sum;
    for (int j = 0; j < 64; ++j) As[tid][j] *= inv;
  }
  __syncthreads();

  // ---- AV: 4x4 register tile, write to x ----
  {
    const int tr = (tid >> 4) * 4;   // output row tile
    const int tt = (tid & 15) * 4;   // output col tile
    float acc[4][4] = {};
    #pragma unroll 4
    for (int j = 0; j < 64; ++j) {
      float av[4], vv[4];
      #pragma unroll
      for (int u = 0; u < 4; ++u) {
        av[u] = As[tr + u][j];
        vv[u] = Qs[j][tt + u];   // Qs holds V now
      }
      #pragma unroll
      for (int ur = 0; ur < 4; ++ur)
        #pragma unroll
        for (int ut = 0; ut < 4; ++ut)
          acc[ur][ut] += av[ur] * vv[ut];
    }
    const int ch = (BR == 0) ? c : (BR == 1) ? (CH + c) : (2 * CH + c);
    float* xo = x + (((size_t)(b * 96 + ch)) << 18);
    #pragma unroll
    for (int ur = 0; ur < 4; ++ur) {
      #pragma unroll
      for (int ut = 0; ut < 4; ++ut) {
        size_t off;
        if (BR == 0) {
          off = (size_t)(tr + ur) * 4096 + (size_t)(tt + ut) * 64 + (size_t)s;
        } else if (BR == 1) {
          off = (size_t)(tr + ur) * 4096 + (size_t)s * 64 + (size_t)(tt + ut);
        } else {
          off = (size_t)s * 4096 + (size_t)(tr + ur) * 64 + (size_t)(tt + ut);
        }
        xo[off] = acc[ur][ut];
      }
    }
  }
}

// ---------------------------------------------------------------------------
// Conv3d 96->32, 3x3x3, SAME + bias + BN(eval) + ReLU.
// Block per (b, co, z); 256 threads = 16x16 (ty, tx); each thread computes a
// 4y x 4x output tile (16 statically-indexed accumulators).
// ---------------------------------------------------------------------------
__global__ __launch_bounds__(256) void conv_bn_relu(const float* __restrict__ xin,
                                                    const float* __restrict__ cw,
                                                    const float* __restrict__ cb,
                                                    const float* __restrict__ gamma,
                                                    const float* __restrict__ beta,
                                                    const float* __restrict__ mean,
                                                    const float* __restrict__ var,
                                                    float* __restrict__ out) {
  const int blk = blockIdx.x;
  const int z = blk & 63;
  const int co = (blk >> 6) & 31;
  const int b = blk >> 11;
  const int tx = threadIdx.x & 15;   // x-tile: x = tx*4 + ox
  const int ty = threadIdx.x >> 4;   // y-tile: y = ty*4 + oy

  float acc[4][4];
  #pragma unroll
  for (int i = 0; i < 4; ++i)
    #pragma unroll
    for (int j = 0; j < 4; ++j) acc[i][j] = 0.f;

  const size_t xin_b = (size_t)b * 96 * 262144;

  for (int ci = 0; ci < 96; ++ci) {
    #pragma unroll
    for (int dz = 0; dz < 3; ++dz) {
      const int zz = z + dz - 1;
      if (zz < 0 || zz > 63) continue;  // uniform branch
      const float* xpz = xin + xin_b + (size_t)ci * 262144 + (size_t)zz * 4096;
      const float* wp = cw + ((size_t)(co * 96 + ci) * 3 + dz) * 9;
      float wreg[9];
      #pragma unroll
      for (int t = 0; t < 9; ++t) wreg[t] = wp[t];  // uniform -> s_loads

      #pragma unroll
      for (int yy = 0; yy < 6; ++yy) {
        const int y = ty * 4 + yy - 1;
        const bool yok = (y >= 0) && (y <= 63);
        float xv[6];
        #pragma unroll
        for (int u = 0; u < 6; ++u) xv[u] = 0.f;
        if (yok) {
          const float* row = xpz + (size_t)y * 64;
          const float4 v4 = *(const float4*)(row + tx * 4);
          xv[1] = v4.x; xv[2] = v4.y; xv[3] = v4.z; xv[4] = v4.w;
          if (tx > 0)  xv[0] = row[tx * 4 - 1];
          if (tx < 15) xv[5] = row[tx * 4 + 4];
        }
        #pragma unroll
        for (int dy = 0; dy < 3; ++dy) {
          const int oy = yy - dy;               // output row index in tile
          if (oy < 0 || oy > 3) continue;       // static after unroll
          #pragma unroll
          for (int ox = 0; ox < 4; ++ox)
            #pragma unroll
            for (int dx = 0; dx < 3; ++dx)
              acc[oy][ox] += wreg[dy * 3 + dx] * xv[ox + dx];
        }
      }
    }
  }

  const float inv = gamma[co] * rsqrtf(var[co] + 1e-5f);
  const float shift = beta[co] - mean[co] * inv;
  const float bias = cb[co];
  float* op = out + (((size_t)(b * CH + co)) << 18) + (size_t)z * 4096;
  #pragma unroll
  for (int oy = 0; oy < 4; ++oy) {
    float4 r;
    r.x = fmaxf(0.f, (acc[oy][0] + bias) * inv + shift);
    r.y = fmaxf(0.f, (acc[oy][1] + bias) * inv + shift);
    r.z = fmaxf(0.f, (acc[oy][2] + bias) * inv + shift);
    r.w = fmaxf(0.f, (acc[oy][3] + bias) * inv + shift);
    *(float4*)(op + (size_t)(ty * 4 + oy) * 64 + tx * 4) = r;
  }
}

extern "C" void kernel_launch(void* const* d_in, const int* in_sizes, int n_in,
                              void* d_out, int out_size, void* d_ws, size_t ws_size,
                              hipStream_t stream) {
  const float* q     = (const float*)d_in[0];
  const float* k     = (const float*)d_in[1];
  const float* v     = (const float*)d_in[2];
  const float* cw    = (const float*)d_in[3];
  const float* cb    = (const float*)d_in[4];
  const float* gamma = (const float*)d_in[5];
  const float* beta  = (const float*)d_in[6];
  const float* mean  = (const float*)d_in[7];
  const float* var   = (const float*)d_in[8];

  float* x   = (float*)d_ws;   // (2, 96, 64, 64, 64) fp32 = 192 MiB
  float* out = (float*)d_out;  // (2, 32, 64, 64, 64) fp32

  dim3 grid(4096), block(256);
  hipLaunchKernelGGL((attn_kernel<0>), grid, block, 0, stream, q, k, v, x);
  hipLaunchKernelGGL((attn_kernel<1>), grid, block, 0, stream, q, k, v, x);
  hipLaunchKernelGGL((attn_kernel<2>), grid, block, 0, stream, q, k, v, x);
  hipLaunchKernelGGL(conv_bn_relu, grid, block, 0, stream,
                     x, cw, cb, gamma, beta, mean, var, out);
}

// Round 4
// 1334.511 us; speedup vs baseline: 3.4813x; 3.4813x over previous
//
#include <hip/hip_runtime.h>
#include <hip/hip_bf16.h>

// BS=2, C=32, S=64.  ws layout (needs 145 MiB; 192 MiB proven available):
//   [0, 48 MiB)      x_bf planar bf16 [96][64^3]   (reused per batch b)
//   [48, 144 MiB)    x_cl channels-last bf16 [2][64^3][96]
//   [144 MiB, +166K) w_t bf16 [27][32][96]
// out: (2,32,64,64,64) fp32.

#define SS 64
#define CH 32
#define CI 96

typedef __attribute__((ext_vector_type(8))) short bf16x8;
typedef __attribute__((ext_vector_type(4))) float f32x4;

static __device__ __forceinline__ unsigned short f2bf(float f) {
  union { float f; unsigned u; } x; x.f = f;
  unsigned r = x.u + 0x7fff + ((x.u >> 16) & 1);   // RNE
  return (unsigned short)(r >> 16);
}

// ---------------------------------------------------------------------------
// Axial attention (fp32 math, unchanged), one block per (c, s) for batch b.
// Emits planar bf16 x_bf[ch=BR*32+c][z][y][x].
// ---------------------------------------------------------------------------
template <int BR>
__global__ __launch_bounds__(256) void attn_kernel(const float* __restrict__ q,
                                                   const float* __restrict__ k,
                                                   const float* __restrict__ v,
                                                   unsigned short* __restrict__ xbf,
                                                   int b) {
  __shared__ float Qs[64][65];
  __shared__ float Ks[64][65];
  __shared__ float As[64][65];

  const int blk = blockIdx.x;
  const int s = blk & 63;
  const int c = blk >> 6;          // 0..31
  const int tid = threadIdx.x;
  const size_t base = ((size_t)(b * CH + c)) << 18;

  for (int idx = tid; idx < 4096; idx += 256) {
    int r, t;
    size_t off;
    if (BR == 0) {
      int m = idx >> 6, i = idx & 63;
      off = (size_t)m * 4096 + (size_t)i * 64 + (size_t)s;
      r = i; t = m;
    } else if (BR == 1) {
      int i = idx >> 6, m = idx & 63;
      off = (size_t)i * 4096 + (size_t)s * 64 + (size_t)m;
      r = i; t = m;
    } else {
      int i = idx >> 6, m = idx & 63;
      off = (size_t)s * 4096 + (size_t)i * 64 + (size_t)m;
      r = i; t = m;
    }
    Qs[r][t] = q[base + off];
    Ks[r][t] = k[base + off];
  }
  __syncthreads();

  {
    const int ti = (tid >> 4) * 4;
    const int tj = (tid & 15) * 4;
    float acc[4][4] = {};
    #pragma unroll 4
    for (int t = 0; t < 64; ++t) {
      float qv[4], kv[4];
      #pragma unroll
      for (int u = 0; u < 4; ++u) { qv[u] = Qs[ti + u][t]; kv[u] = Ks[tj + u][t]; }
      #pragma unroll
      for (int ui = 0; ui < 4; ++ui)
        #pragma unroll
        for (int uj = 0; uj < 4; ++uj)
          acc[ui][uj] += qv[ui] * kv[uj];
    }
    #pragma unroll
    for (int ui = 0; ui < 4; ++ui)
      #pragma unroll
      for (int uj = 0; uj < 4; ++uj)
        As[ti + ui][tj + uj] = acc[ui][uj];
  }
  __syncthreads();

  for (int idx = tid; idx < 4096; idx += 256) {
    int r, t;
    size_t off;
    if (BR == 0) {
      int j = idx >> 6, w = idx & 63;
      off = (size_t)j * 4096 + (size_t)w * 64 + (size_t)s;
      r = j; t = w;
    } else if (BR == 1) {
      int j = idx >> 6, m = idx & 63;
      off = (size_t)j * 4096 + (size_t)s * 64 + (size_t)m;
      r = j; t = m;
    } else {
      int j = idx >> 6, m = idx & 63;
      off = (size_t)s * 4096 + (size_t)j * 64 + (size_t)m;
      r = j; t = m;
    }
    Qs[r][t] = v[base + off];
  }
  if (tid < 64) {
    float mx = -1e30f;
    for (int j = 0; j < 64; ++j) mx = fmaxf(mx, As[tid][j]);
    float sum = 0.f;
    for (int j = 0; j < 64; ++j) {
      float e = __expf(As[tid][j] - mx);
      As[tid][j] = e;
      sum += e;
    }
    float inv = 1.f / sum;
    for (int j = 0; j < 64; ++j) As[tid][j] *= inv;
  }
  __syncthreads();

  {
    const int tr = (tid >> 4) * 4;
    const int tt = (tid & 15) * 4;
    float acc[4][4] = {};
    #pragma unroll 4
    for (int j = 0; j < 64; ++j) {
      float av[4], vv[4];
      #pragma unroll
      for (int u = 0; u < 4; ++u) { av[u] = As[tr + u][j]; vv[u] = Qs[j][tt + u]; }
      #pragma unroll
      for (int ur = 0; ur < 4; ++ur)
        #pragma unroll
        for (int ut = 0; ut < 4; ++ut)
          acc[ur][ut] += av[ur] * vv[ut];
    }
    const int ch = BR * CH + c;
    unsigned short* xo = xbf + ((size_t)ch << 18);
    #pragma unroll
    for (int ur = 0; ur < 4; ++ur) {
      #pragma unroll
      for (int ut = 0; ut < 4; ++ut) {
        size_t off;
        if (BR == 0) {
          off = (size_t)(tr + ur) * 4096 + (size_t)(tt + ut) * 64 + (size_t)s;
        } else if (BR == 1) {
          off = (size_t)(tr + ur) * 4096 + (size_t)s * 64 + (size_t)(tt + ut);
        } else {
          off = (size_t)s * 4096 + (size_t)(tr + ur) * 64 + (size_t)(tt + ut);
        }
        xo[off] = f2bf(acc[ur][ut]);
      }
    }
  }
}

// ---------------------------------------------------------------------------
// Repack planar bf16 [96][262144] -> channels-last [262144][96] (one batch).
// Block = (z, 256-position chunk). LDS transpose: [sp][ch], pad 96->104 so
// row stride 208 B is 16B-aligned for b128 reads.
// ---------------------------------------------------------------------------
__global__ __launch_bounds__(256) void repack(const unsigned short* __restrict__ src,
                                              unsigned short* __restrict__ dst) {
  __shared__ unsigned short L[256][104];
  const int blk = blockIdx.x;       // 1024
  const int chunk = blk & 15;
  const int z = blk >> 4;
  const int tid = threadIdx.x;
  const int sp0 = (z << 12) + (chunk << 8);

  #pragma unroll
  for (int i = 0; i < 12; ++i) {
    int li = i * 256 + tid;         // 0..3071
    int ch = li >> 5;               // 0..95
    int spo = (li & 31) * 8;
    bf16x8 vv = *(const bf16x8*)(src + (size_t)ch * 262144 + sp0 + spo);
    #pragma unroll
    for (int j = 0; j < 8; ++j) L[spo + j][ch] = (unsigned short)vv[j];
  }
  __syncthreads();
  #pragma unroll
  for (int i = 0; i < 12; ++i) {
    bf16x8 vv = *(const bf16x8*)&L[tid][i * 8];
    *(bf16x8*)(dst + (size_t)(sp0 + tid) * CI + i * 8) = vv;
  }
}

// w[co][ci][dz][dy][dx] f32 -> w_t[tap][co][ci] bf16
__global__ __launch_bounds__(256) void wprep(const float* __restrict__ w,
                                             unsigned short* __restrict__ wt) {
  int idx = blockIdx.x * 256 + threadIdx.x;
  if (idx >= 27 * 32 * 96) return;
  int tap = idx / (32 * 96);
  int rem = idx - tap * (32 * 96);
  int co = rem / 96, ci = rem - co * 96;
  wt[idx] = f2bf(w[((size_t)co * 96 + ci) * 27 + tap]);
}

// ---------------------------------------------------------------------------
// Implicit-GEMM conv via mfma_f32_16x16x32_bf16.
// Block = (b, z, y-quarter): 16y x 64x spatial, all 32 co. 8 waves; wave owns
// 2 y-rows x 4 x-chunks (8 n-tiles) x 2 co-tiles -> acc[2][4][2] f32x4.
// A-frag: lane r=x-in-tile (row), oct=lane>>4 -> 8 contiguous ci (16B load).
// B-frag: lane r=co (col),      oct          -> 8 contiguous ci of w_t.
// D: co = lane&15, x = xc*16 + oct*4 + reg.
// ---------------------------------------------------------------------------
__global__ __launch_bounds__(512) void conv_mfma(const unsigned short* __restrict__ xcl,
                                                 const unsigned short* __restrict__ wt,
                                                 const float* __restrict__ cb,
                                                 const float* __restrict__ gamma,
                                                 const float* __restrict__ beta,
                                                 const float* __restrict__ mean,
                                                 const float* __restrict__ var,
                                                 float* __restrict__ out) {
  const int blk = blockIdx.x;        // 512
  const int yq = blk & 3;
  const int z = (blk >> 2) & 63;
  const int b = blk >> 8;
  const int tid = threadIdx.x;
  const int w = tid >> 6;            // wave 0..7
  const int lane = tid & 63;
  const int r = lane & 15;
  const int oct = lane >> 4;         // 0..3
  const int ywave = yq * 16 + w * 2;

  const unsigned short* xb = xcl + (size_t)b * (262144ull * CI);
  const int lane_ci = oct * 8;

  f32x4 acc[2][4][2];
  #pragma unroll
  for (int ry = 0; ry < 2; ++ry)
    #pragma unroll
    for (int xc = 0; xc < 4; ++xc)
      #pragma unroll
      for (int ct = 0; ct < 2; ++ct)
        acc[ry][xc][ct] = (f32x4){0.f, 0.f, 0.f, 0.f};

  for (int dz = 0; dz < 3; ++dz) {
    const int zz = z + dz - 1;
    if ((unsigned)zz > 63u) continue;
    const unsigned short* xz = xb + (size_t)zz * (4096ull * CI);
    for (int dy = 0; dy < 3; ++dy) {
      #pragma unroll
      for (int dx = 0; dx < 3; ++dx) {
        const int tap = (dz * 3 + dy) * 3 + dx;
        const unsigned short* wp = wt + (size_t)tap * 32 * CI;
        bf16x8 wf[2][3];
        #pragma unroll
        for (int ct = 0; ct < 2; ++ct)
          #pragma unroll
          for (int ks = 0; ks < 3; ++ks)
            wf[ct][ks] = *(const bf16x8*)(wp + (size_t)(ct * 16 + r) * CI + ks * 32 + lane_ci);
        #pragma unroll
        for (int ry = 0; ry < 2; ++ry) {
          const int yy = ywave + ry + dy - 1;
          if ((unsigned)yy > 63u) continue;
          const unsigned short* xrow = xz + (size_t)yy * (64 * CI);
          #pragma unroll
          for (int xc = 0; xc < 4; ++xc) {
            const int xx = xc * 16 + r + dx - 1;
            const bool ok = (unsigned)xx < 64u;
            const unsigned short* pa = xrow + (size_t)xx * CI + lane_ci;
            #pragma unroll
            for (int ks = 0; ks < 3; ++ks) {
              bf16x8 af;
              #pragma unroll
              for (int j = 0; j < 8; ++j) af[j] = 0;
              if (ok) af = *(const bf16x8*)(pa + ks * 32);
              acc[ry][xc][0] = __builtin_amdgcn_mfma_f32_16x16x32_bf16(af, wf[0][ks], acc[ry][xc][0], 0, 0, 0);
              acc[ry][xc][1] = __builtin_amdgcn_mfma_f32_16x16x32_bf16(af, wf[1][ks], acc[ry][xc][1], 0, 0, 0);
            }
          }
        }
      }
    }
  }

  // epilogue: bias + BN + ReLU, float4 stores (x = xc*16 + oct*4 .. +3)
  float invc[2], shc[2], bic[2];
  #pragma unroll
  for (int ct = 0; ct < 2; ++ct) {
    const int co = ct * 16 + r;
    const float iv = gamma[co] * rsqrtf(var[co] + 1e-5f);
    invc[ct] = iv;
    shc[ct] = beta[co] - mean[co] * iv;
    bic[ct] = cb[co];
  }
  #pragma unroll
  for (int ct = 0; ct < 2; ++ct) {
    float* oc = out + (((size_t)(b * CH + ct * 16 + r)) << 18) + ((size_t)z << 12);
    #pragma unroll
    for (int ry = 0; ry < 2; ++ry) {
      #pragma unroll
      for (int xc = 0; xc < 4; ++xc) {
        const f32x4 a = acc[ry][xc][ct];
        float4 st;
        st.x = fmaxf(0.f, (a[0] + bic[ct]) * invc[ct] + shc[ct]);
        st.y = fmaxf(0.f, (a[1] + bic[ct]) * invc[ct] + shc[ct]);
        st.z = fmaxf(0.f, (a[2] + bic[ct]) * invc[ct] + shc[ct]);
        st.w = fmaxf(0.f, (a[3] + bic[ct]) * invc[ct] + shc[ct]);
        *(float4*)(oc + (size_t)(ywave + ry) * 64 + xc * 16 + oct * 4) = st;
      }
    }
  }
}

extern "C" void kernel_launch(void* const* d_in, const int* in_sizes, int n_in,
                              void* d_out, int out_size, void* d_ws, size_t ws_size,
                              hipStream_t stream) {
  const float* q     = (const float*)d_in[0];
  const float* k     = (const float*)d_in[1];
  const float* v     = (const float*)d_in[2];
  const float* cw    = (const float*)d_in[3];
  const float* cb    = (const float*)d_in[4];
  const float* gamma = (const float*)d_in[5];
  const float* beta  = (const float*)d_in[6];
  const float* mean  = (const float*)d_in[7];
  const float* var   = (const float*)d_in[8];

  unsigned short* xbf = (unsigned short*)d_ws;                                   // 48 MiB
  unsigned short* xcl = (unsigned short*)((char*)d_ws + (48ull << 20));          // 96 MiB
  unsigned short* wtp = (unsigned short*)((char*)d_ws + (144ull << 20));         // 166 KB
  float* out = (float*)d_out;

  hipLaunchKernelGGL(wprep, dim3(324), dim3(256), 0, stream, cw, wtp);
  for (int b = 0; b < 2; ++b) {
    hipLaunchKernelGGL((attn_kernel<0>), dim3(2048), dim3(256), 0, stream, q, k, v, xbf, b);
    hipLaunchKernelGGL((attn_kernel<1>), dim3(2048), dim3(256), 0, stream, q, k, v, xbf, b);
    hipLaunchKernelGGL((attn_kernel<2>), dim3(2048), dim3(256), 0, stream, q, k, v, xbf, b);
    hipLaunchKernelGGL(repack, dim3(1024), dim3(256), 0, stream,
                       xbf, xcl + (size_t)b * 262144ull * CI);
  }
  hipLaunchKernelGGL(conv_mfma, dim3(512), dim3(512), 0, stream,
                     xcl, wtp, cb, gamma, beta, mean, var, out);
}